// Round 1
// baseline (7368.760 us; speedup 1.0000x reference)
//
#include <hip/hip_runtime.h>
#include <hip/hip_bf16.h>

#define B_ 64
#define T_ 2048
#define DIN_ 128
#define H_ 256
#define DOUT_ 128

typedef __bf16 bf16x8 __attribute__((ext_vector_type(8)));
typedef unsigned short u16x8 __attribute__((ext_vector_type(8)));
typedef float f32x4 __attribute__((ext_vector_type(4)));

__device__ __forceinline__ unsigned short f2bf(float f) {
    union { float f; unsigned u; } v; v.f = f;
    unsigned r = v.u + 0x7FFFu + ((v.u >> 16) & 1u);   // round-to-nearest-even
    return (unsigned short)(r >> 16);
}
__device__ __forceinline__ float bf2f(unsigned short b) {
    union { unsigned u; float f; } v; v.u = ((unsigned)b) << 16;
    return v.f;
}
__device__ __forceinline__ bf16x8 ld8f_bf(const float* p) {
    float4 a = *(const float4*)p;
    float4 b = *(const float4*)(p + 4);
    u16x8 u;
    u[0] = f2bf(a.x); u[1] = f2bf(a.y); u[2] = f2bf(a.z); u[3] = f2bf(a.w);
    u[4] = f2bf(b.x); u[5] = f2bf(b.y); u[6] = f2bf(b.z); u[7] = f2bf(b.w);
    return __builtin_bit_cast(bf16x8, u);
}
__device__ __forceinline__ float tanh_fast(float x) {
    float xc = fminf(9.0f, fmaxf(-9.0f, x));          // tanh(±9) == ±1 in bf16
    float e = __expf(2.0f * xc);
    return (e - 1.0f) * __builtin_amdgcn_rcpf(e + 1.0f);
}

// -------- kernel 1: Pre0[t][b][n] = b0[n] + sum_k x[b][t][k] * Wx0[n][k]  (bf16 out)
__global__ __launch_bounds__(256) void k_pre(const float* __restrict__ x,
                                             const float* __restrict__ Wx0,
                                             const float* __restrict__ b0,
                                             unsigned short* __restrict__ Pre0) {
    const int t  = blockIdx.x;
    const int bc = blockIdx.y;             // 16-row batch chunk
    const int w  = threadIdx.x >> 6;
    const int l  = threadIdx.x & 63;
    const int lr = l & 15, lg = l >> 4;

    // A fragments: x rows, K=128 -> 4 k-steps of 32
    bf16x8 af[4];
    const float* xrow = x + ((size_t)(bc * 16 + lr) * T_ + t) * DIN_ + lg * 8;
#pragma unroll
    for (int kk = 0; kk < 4; kk++) af[kk] = ld8f_bf(xrow + kk * 32);

#pragma unroll
    for (int i = 0; i < 4; i++) {
        const int n0 = (w + 4 * i) * 16;   // wave handles 4 of 16 n-tiles
        const float* wrow = Wx0 + (size_t)(n0 + lr) * DIN_ + lg * 8;
        bf16x8 bfr[4];
#pragma unroll
        for (int kk = 0; kk < 4; kk++) bfr[kk] = ld8f_bf(wrow + kk * 32);
        float bias = b0[n0 + lr];
        f32x4 acc = { bias, bias, bias, bias };
#pragma unroll
        for (int kk = 0; kk < 4; kk++)
            acc = __builtin_amdgcn_mfma_f32_16x16x32_bf16(af[kk], bfr[kk], acc, 0, 0, 0);
        unsigned short* orow = Pre0 + ((size_t)t * B_ + bc * 16) * H_;
#pragma unroll
        for (int j = 0; j < 4; j++) {
            int row = lg * 4 + j;
            orow[(size_t)row * H_ + n0 + lr] = f2bf(acc[j]);
        }
    }
}

// -------- kernel 2: sequential scan. 4 blocks x 16 batch rows; 8 waves x 32 cols.
// Weights register-resident as B-fragments; state double-buffered in swizzled LDS.
__global__ __launch_bounds__(512, 2) void k_scan(const float* __restrict__ h0in,
                                                 const float* __restrict__ Wh0,
                                                 const float* __restrict__ Wx1,
                                                 const float* __restrict__ Wh1,
                                                 const float* __restrict__ b1,
                                                 const unsigned short* __restrict__ Pre0,
                                                 unsigned short* __restrict__ H1) {
    const int g   = blockIdx.x;
    const int m0  = g * 16;
    const int tid = threadIdx.x;
    const int w   = tid >> 6, l = tid & 63;
    const int lr  = l & 15, lg = l >> 4;
    const int n0  = w * 32;

    __shared__ __align__(16) unsigned short h0s[2][16][256];
    __shared__ __align__(16) unsigned short h1s[2][16][256];

    // load weight B-fragments (one-time): B[k][n] = W[n][k]; lane holds 8 contiguous k
    bf16x8 wh0f[2][8], wx1f[2][8], wh1f[2][8];
#pragma unroll
    for (int u = 0; u < 2; u++) {
        const int n = n0 + u * 16 + lr;
#pragma unroll
        for (int kk = 0; kk < 8; kk++) {
            const int k0 = kk * 32 + lg * 8;
            wh0f[u][kk] = ld8f_bf(Wh0 + (size_t)n * H_ + k0);
            wx1f[u][kk] = ld8f_bf(Wx1 + (size_t)n * H_ + k0);
            wh1f[u][kk] = ld8f_bf(Wh1 + (size_t)n * H_ + k0);
        }
    }
    float b1v[2] = { b1[n0 + lr], b1[n0 + 16 + lr] };

    // init state into swizzled LDS (chunk-XOR: 16B chunk c of row r stored at c^(r&7))
    for (int i = tid; i < 16 * 256; i += 512) {
        int r = i >> 8, e = i & 255;
        int sw = (((e >> 3) ^ (r & 7)) << 3) | (e & 7);
        h0s[0][r][sw] = f2bf(h0in[(size_t)(m0 + r) * H_ + e]);
        h1s[0][r][sw] = f2bf(h0in[(size_t)(B_ + m0 + r) * H_ + e]);
    }
    __syncthreads();

    // prefetch Pre0 for t=0 (C/D layout: row = lg*4+j, col = lr)
    unsigned short pre[2][4];
#pragma unroll
    for (int u = 0; u < 2; u++)
#pragma unroll
        for (int j = 0; j < 4; j++)
            pre[u][j] = Pre0[((size_t)0 * B_ + m0 + lg * 4 + j) * H_ + n0 + u * 16 + lr];

    int cur = 0;
    for (int t = 0; t < T_; t++) {
        const int nxt = cur ^ 1;
        // ---- layer 0: h0n = tanh(Pre0 + h0 @ Wh0^T)
        f32x4 acc0, acc1;
#pragma unroll
        for (int j = 0; j < 4; j++) { acc0[j] = bf2f(pre[0][j]); acc1[j] = bf2f(pre[1][j]); }
#pragma unroll
        for (int kk = 0; kk < 8; kk++) {
            const int c = (((kk * 4 + lg) ^ (lr & 7)) << 3);
            bf16x8 a = __builtin_bit_cast(bf16x8, *(const u16x8*)&h0s[cur][lr][c]);
            acc0 = __builtin_amdgcn_mfma_f32_16x16x32_bf16(a, wh0f[0][kk], acc0, 0, 0, 0);
            acc1 = __builtin_amdgcn_mfma_f32_16x16x32_bf16(a, wh0f[1][kk], acc1, 0, 0, 0);
        }
        // prefetch next step's Pre0 (hides HBM latency under tanh + layer 1)
        if (t + 1 < T_) {
#pragma unroll
            for (int u = 0; u < 2; u++)
#pragma unroll
                for (int j = 0; j < 4; j++)
                    pre[u][j] = Pre0[((size_t)(t + 1) * B_ + m0 + lg * 4 + j) * H_ + n0 + u * 16 + lr];
        }
        // tanh + write h0 new state (C/D layout -> swizzled LDS scalar writes)
#pragma unroll
        for (int j = 0; j < 4; j++) {
            const int r = lg * 4 + j;
            {
                float v = tanh_fast(acc0[j]);
                int e = n0 + lr;
                h0s[nxt][r][(((e >> 3) ^ (r & 7)) << 3) | (e & 7)] = f2bf(v);
            }
            {
                float v = tanh_fast(acc1[j]);
                int e = n0 + 16 + lr;
                h0s[nxt][r][(((e >> 3) ^ (r & 7)) << 3) | (e & 7)] = f2bf(v);
            }
        }
        __syncthreads();
        // ---- layer 1: h1n = tanh(h0n @ Wx1^T + h1 @ Wh1^T + b1)
        f32x4 d0 = { b1v[0], b1v[0], b1v[0], b1v[0] };
        f32x4 d1 = { b1v[1], b1v[1], b1v[1], b1v[1] };
#pragma unroll
        for (int kk = 0; kk < 8; kk++) {
            const int c = (((kk * 4 + lg) ^ (lr & 7)) << 3);
            bf16x8 a0 = __builtin_bit_cast(bf16x8, *(const u16x8*)&h0s[nxt][lr][c]);
            d0 = __builtin_amdgcn_mfma_f32_16x16x32_bf16(a0, wx1f[0][kk], d0, 0, 0, 0);
            d1 = __builtin_amdgcn_mfma_f32_16x16x32_bf16(a0, wx1f[1][kk], d1, 0, 0, 0);
            bf16x8 a1 = __builtin_bit_cast(bf16x8, *(const u16x8*)&h1s[cur][lr][c]);
            d0 = __builtin_amdgcn_mfma_f32_16x16x32_bf16(a1, wh1f[0][kk], d0, 0, 0, 0);
            d1 = __builtin_amdgcn_mfma_f32_16x16x32_bf16(a1, wh1f[1][kk], d1, 0, 0, 0);
        }
        unsigned short* hout = H1 + ((size_t)t * B_ + m0) * H_;
#pragma unroll
        for (int j = 0; j < 4; j++) {
            const int r = lg * 4 + j;
            {
                float v = tanh_fast(d0[j]);
                unsigned short bv = f2bf(v);
                int e = n0 + lr;
                h1s[nxt][r][(((e >> 3) ^ (r & 7)) << 3) | (e & 7)] = bv;
                hout[(size_t)r * H_ + e] = bv;
            }
            {
                float v = tanh_fast(d1[j]);
                unsigned short bv = f2bf(v);
                int e = n0 + 16 + lr;
                h1s[nxt][r][(((e >> 3) ^ (r & 7)) << 3) | (e & 7)] = bv;
                hout[(size_t)r * H_ + e] = bv;
            }
        }
        __syncthreads();
        cur = nxt;
    }
}

// -------- kernel 3: Y[b][t][d] = bout[d] + sum_k H1[t][b][k] * Wout[d][k]  (fp32 out)
__global__ __launch_bounds__(256) void k_out(const unsigned short* __restrict__ H1,
                                             const float* __restrict__ Wout,
                                             const float* __restrict__ bout,
                                             float* __restrict__ out) {
    const int t  = blockIdx.x;
    const int bc = blockIdx.y;
    const int w  = threadIdx.x >> 6;
    const int l  = threadIdx.x & 63;
    const int lr = l & 15, lg = l >> 4;

    bf16x8 af[8];
    const unsigned short* hrow = H1 + ((size_t)t * B_ + bc * 16 + lr) * H_ + lg * 8;
#pragma unroll
    for (int kk = 0; kk < 8; kk++)
        af[kk] = __builtin_bit_cast(bf16x8, *(const u16x8*)(hrow + kk * 32));

#pragma unroll
    for (int i = 0; i < 2; i++) {
        const int n0 = (w + 4 * i) * 16;   // DOUT=128 -> 8 tiles over 4 waves
        const float* wrow = Wout + (size_t)(n0 + lr) * H_ + lg * 8;
        float bias = bout[n0 + lr];
        f32x4 acc = { bias, bias, bias, bias };
#pragma unroll
        for (int kk = 0; kk < 8; kk++) {
            bf16x8 bfr = ld8f_bf(wrow + kk * 32);
            acc = __builtin_amdgcn_mfma_f32_16x16x32_bf16(af[kk], bfr, acc, 0, 0, 0);
        }
#pragma unroll
        for (int j = 0; j < 4; j++) {
            int row = lg * 4 + j;
            out[((size_t)(bc * 16 + row) * T_ + t) * DOUT_ + n0 + lr] = acc[j];
        }
    }
}

extern "C" void kernel_launch(void* const* d_in, const int* in_sizes, int n_in,
                              void* d_out, int out_size, void* d_ws, size_t ws_size,
                              hipStream_t stream) {
    const float* x    = (const float*)d_in[0];
    const float* h0   = (const float*)d_in[1];
    const float* Wx0  = (const float*)d_in[2];
    const float* Wh0  = (const float*)d_in[3];
    const float* b0   = (const float*)d_in[4];
    const float* Wx1  = (const float*)d_in[5];
    const float* Wh1  = (const float*)d_in[6];
    const float* b1   = (const float*)d_in[7];
    const float* Wout = (const float*)d_in[8];
    const float* bout = (const float*)d_in[9];
    float* out = (float*)d_out;

    // ws layout: Pre0 bf16 (T,B,H) = 64MB, then H1 bf16 (T,B,H) = 64MB
    unsigned short* Pre0 = (unsigned short*)d_ws;
    unsigned short* H1   = Pre0 + (size_t)T_ * B_ * H_;

    k_pre<<<dim3(T_, B_ / 16), 256, 0, stream>>>(x, Wx0, b0, Pre0);
    k_scan<<<dim3(4), 512, 0, stream>>>(h0, Wh0, Wx1, Wh1, b1, Pre0, H1);
    k_out<<<dim3(T_, B_ / 16), 256, 0, stream>>>(H1, Wout, bout, out);
}

// Round 2
// 3402.338 us; speedup vs baseline: 2.1658x; 2.1658x over previous
//
#include <hip/hip_runtime.h>
#include <hip/hip_bf16.h>

#define B_ 64
#define T_ 2048
#define DIN_ 128
#define H_ 256
#define DOUT_ 128

typedef __bf16 bf16x8 __attribute__((ext_vector_type(8)));
typedef unsigned short u16x8 __attribute__((ext_vector_type(8)));
typedef unsigned short u16x4 __attribute__((ext_vector_type(4)));
typedef unsigned int u32x2 __attribute__((ext_vector_type(2)));
typedef float f32x4 __attribute__((ext_vector_type(4)));

static __device__ __forceinline__ unsigned short f2bf(float f) {
    union { float f; unsigned u; } v; v.f = f;
    unsigned r = v.u + 0x7FFFu + ((v.u >> 16) & 1u);   // RNE
    return (unsigned short)(r >> 16);
}
static __device__ __forceinline__ float bf2f(unsigned short b) {
    union { unsigned u; float f; } v; v.u = ((unsigned)b) << 16;
    return v.f;
}
static __device__ __forceinline__ unsigned cvt_pk_bf16(float lo, float hi) {
    unsigned r;
    asm("v_cvt_pk_bf16_f32 %0, %1, %2" : "=v"(r) : "v"(lo), "v"(hi));
    return r;
}
static __device__ __forceinline__ float tanh_fast(float x) {
    // tanh(x) = sign(x) * (1-e)/(1+e), e = 2^(-2*log2e*|x|) in (0,1] -> no clamp needed
    float e = __builtin_amdgcn_exp2f(-2.8853900817779268f * __builtin_fabsf(x));
    float t = (1.0f - e) * __builtin_amdgcn_rcpf(1.0f + e);
    return __builtin_copysignf(t, x);
}
static __device__ __forceinline__ bf16x8 ld8f_bf(const float* p) {
    float4 a = *(const float4*)p;
    float4 b = *(const float4*)(p + 4);
    u16x8 u;
    u[0] = f2bf(a.x); u[1] = f2bf(a.y); u[2] = f2bf(a.z); u[3] = f2bf(a.w);
    u[4] = f2bf(b.x); u[5] = f2bf(b.y); u[6] = f2bf(b.z); u[7] = f2bf(b.w);
    return __builtin_bit_cast(bf16x8, u);
}

// -------- kernel 1 (swapped): Pre0[t][b][n] = b0[n] + sum_k x[b][t][k]*Wx0[n][k]
// mfma(A=Wx0 rows, B=x^T) -> lane holds 4 contiguous n at fixed b -> b64 stores.
__global__ __launch_bounds__(256) void k_pre(const float* __restrict__ x,
                                             const float* __restrict__ Wx0,
                                             const float* __restrict__ b0,
                                             unsigned short* __restrict__ Pre0) {
    const int t  = blockIdx.x;
    const int bc = blockIdx.y;
    const int w  = threadIdx.x >> 6;
    const int l  = threadIdx.x & 63;
    const int lr = l & 15, lg = l >> 4;

    bf16x8 af[4];
    const float* xrow = x + ((size_t)(bc * 16 + lr) * T_ + t) * DIN_ + lg * 8;
#pragma unroll
    for (int kk = 0; kk < 4; kk++) af[kk] = ld8f_bf(xrow + kk * 32);

    unsigned short* op = Pre0 + ((size_t)t * B_ + bc * 16 + lr) * H_;

#pragma unroll
    for (int i = 0; i < 4; i++) {
        const int n0 = (w + 4 * i) * 16;
        const float* wrow = Wx0 + (size_t)(n0 + lr) * DIN_ + lg * 8;
        bf16x8 bfr[4];
#pragma unroll
        for (int kk = 0; kk < 4; kk++) bfr[kk] = ld8f_bf(wrow + kk * 32);
        float4 bv = *(const float4*)&b0[n0 + lg * 4];
        f32x4 acc = { bv.x, bv.y, bv.z, bv.w };
#pragma unroll
        for (int kk = 0; kk < 4; kk++)
            acc = __builtin_amdgcn_mfma_f32_16x16x32_bf16(bfr[kk], af[kk], acc, 0, 0, 0);
        u32x2 pk;
        pk[0] = cvt_pk_bf16(acc[0], acc[1]);
        pk[1] = cvt_pk_bf16(acc[2], acc[3]);
        *(u32x2*)&op[n0 + lg * 4] = pk;
    }
}

// -------- kernel 2: sequential scan, all-MFMA-swapped, single barrier/step.
__global__ __launch_bounds__(512, 2) void k_scan(const float* __restrict__ h0in,
                                                 const float* __restrict__ Wh0,
                                                 const float* __restrict__ Wx1,
                                                 const float* __restrict__ Wh1,
                                                 const float* __restrict__ b1,
                                                 const unsigned short* __restrict__ Pre0,
                                                 unsigned short* __restrict__ H1) {
    const int m0  = blockIdx.x * 16;
    const int tid = threadIdx.x;
    const int w   = tid >> 6, l = tid & 63;
    const int lr  = l & 15, lg = l >> 4;
    const int n0  = w * 32;

    __shared__ __align__(16) unsigned short h0s[2][16][256];
    __shared__ __align__(16) unsigned short h1s[2][16][256];

    // weight fragments: lane = W[n = n0+u*16+l&15][k = lg*8 .. +7] (A-frag, rows = n)
    bf16x8 wh0f[2][8], wx1f[2][8], wh1f[2][8];
#pragma unroll
    for (int u = 0; u < 2; u++) {
        const int n = n0 + u * 16 + lr;
#pragma unroll
        for (int kk = 0; kk < 8; kk++) {
            const int k0 = kk * 32 + lg * 8;
            wh0f[u][kk] = ld8f_bf(Wh0 + (size_t)n * H_ + k0);
            wx1f[u][kk] = ld8f_bf(Wx1 + (size_t)n * H_ + k0);
            wh1f[u][kk] = ld8f_bf(Wh1 + (size_t)n * H_ + k0);
        }
    }
    // bias per accumulator row n = n0+u*16+lg*4+j
    float4 b1q0 = *(const float4*)&b1[n0 + lg * 4];
    float4 b1q1 = *(const float4*)&b1[n0 + 16 + lg * 4];

    // init state (swizzled row-major [b][n], XOR on 8-u16 chunks)
    for (int i = tid; i < 16 * 256; i += 512) {
        int r = i >> 8, e = i & 255;
        int sw = (((e >> 3) ^ (r & 7)) << 3) | (e & 7);
        h0s[0][r][sw] = f2bf(h0in[(size_t)(m0 + r) * H_ + e]);
        h1s[0][r][sw] = f2bf(h0in[(size_t)(B_ + m0 + r) * H_ + e]);
    }

    // Pre0 / H1 pointers: lane covers (b = m0+lr, n = n0+u*16+lg*4 .. +3)
    const unsigned short* prep = Pre0 + (size_t)(m0 + lr) * H_ + n0 + lg * 4;
    unsigned short* h1p = H1 + (size_t)(m0 + lr) * H_ + n0 + lg * 4;
    u16x4 pv0 = *(const u16x4*)prep;
    u16x4 pv1 = *(const u16x4*)(prep + 16);
    prep += B_ * H_;

    __syncthreads();

    const int swm = lr & 7;
    const int e0w = n0 + lg * 4;
    const int e1w = n0 + 16 + lg * 4;
    const int sw0 = (((e0w >> 3) ^ swm) << 3) | (e0w & 7);
    const int sw1 = (((e1w >> 3) ^ swm) << 3) | (e1w & 7);

    int cur = 0;
    for (int t = 0; t < T_; t++) {
        const int nxt = cur ^ 1;
        // ---- layer 0: h0n^T = Wh0 . h0^T + Pre0^T ; 4 independent chains
        f32x4 a00, a01, a10, a11;
#pragma unroll
        for (int j = 0; j < 4; j++) {
            a00[j] = bf2f(pv0[j]); a10[j] = bf2f(pv1[j]);
            a01[j] = 0.0f;         a11[j] = 0.0f;
        }
#pragma unroll
        for (int kk = 0; kk < 4; kk++) {
            const int c  = (((kk * 4 + lg) ^ swm) << 3);
            const int c2 = ((((kk + 4) * 4 + lg) ^ swm) << 3);
            bf16x8 s0 = __builtin_bit_cast(bf16x8, *(const u16x8*)&h0s[cur][lr][c]);
            bf16x8 s1 = __builtin_bit_cast(bf16x8, *(const u16x8*)&h0s[cur][lr][c2]);
            a00 = __builtin_amdgcn_mfma_f32_16x16x32_bf16(wh0f[0][kk],     s0, a00, 0, 0, 0);
            a10 = __builtin_amdgcn_mfma_f32_16x16x32_bf16(wh0f[1][kk],     s0, a10, 0, 0, 0);
            a01 = __builtin_amdgcn_mfma_f32_16x16x32_bf16(wh0f[0][kk + 4], s1, a01, 0, 0, 0);
            a11 = __builtin_amdgcn_mfma_f32_16x16x32_bf16(wh0f[1][kk + 4], s1, a11, 0, 0, 0);
        }
        // prefetch next step's Pre0 (reads 8B past region at t=2047 -> lands in H1, harmless)
        pv0 = *(const u16x4*)prep;
        pv1 = *(const u16x4*)(prep + 16);
        prep += B_ * H_;

        f32x4 h0a = a00 + a01, h0b = a10 + a11;
        u32x2 pk0, pk1;
        pk0[0] = cvt_pk_bf16(tanh_fast(h0a[0]), tanh_fast(h0a[1]));
        pk0[1] = cvt_pk_bf16(tanh_fast(h0a[2]), tanh_fast(h0a[3]));
        pk1[0] = cvt_pk_bf16(tanh_fast(h0b[0]), tanh_fast(h0b[1]));
        pk1[1] = cvt_pk_bf16(tanh_fast(h0b[2]), tanh_fast(h0b[3]));
        *(u32x2*)&h0s[nxt][lr][sw0] = pk0;
        *(u32x2*)&h0s[nxt][lr][sw1] = pk1;

        __syncthreads();   // single barrier per step (h1 dbl-buffer races ordered by next iter's barrier)

        // ---- layer 1: h1n^T = Wx1 . h0n^T + Wh1 . h1^T + b1 ; 4 chains
        f32x4 dA0 = { b1q0.x, b1q0.y, b1q0.z, b1q0.w };
        f32x4 dA1 = { b1q1.x, b1q1.y, b1q1.z, b1q1.w };
        f32x4 dB0 = { 0.0f, 0.0f, 0.0f, 0.0f };
        f32x4 dB1 = { 0.0f, 0.0f, 0.0f, 0.0f };
#pragma unroll
        for (int kk = 0; kk < 8; kk++) {
            const int c = (((kk * 4 + lg) ^ swm) << 3);
            bf16x8 s0 = __builtin_bit_cast(bf16x8, *(const u16x8*)&h0s[nxt][lr][c]);
            dA0 = __builtin_amdgcn_mfma_f32_16x16x32_bf16(wx1f[0][kk], s0, dA0, 0, 0, 0);
            dA1 = __builtin_amdgcn_mfma_f32_16x16x32_bf16(wx1f[1][kk], s0, dA1, 0, 0, 0);
            bf16x8 s1 = __builtin_bit_cast(bf16x8, *(const u16x8*)&h1s[cur][lr][c]);
            dB0 = __builtin_amdgcn_mfma_f32_16x16x32_bf16(wh1f[0][kk], s1, dB0, 0, 0, 0);
            dB1 = __builtin_amdgcn_mfma_f32_16x16x32_bf16(wh1f[1][kk], s1, dB1, 0, 0, 0);
        }
        f32x4 h1a = dA0 + dB0, h1b = dA1 + dB1;
        pk0[0] = cvt_pk_bf16(tanh_fast(h1a[0]), tanh_fast(h1a[1]));
        pk0[1] = cvt_pk_bf16(tanh_fast(h1a[2]), tanh_fast(h1a[3]));
        pk1[0] = cvt_pk_bf16(tanh_fast(h1b[0]), tanh_fast(h1b[1]));
        pk1[1] = cvt_pk_bf16(tanh_fast(h1b[2]), tanh_fast(h1b[3]));
        *(u32x2*)&h1s[nxt][lr][sw0] = pk0;
        *(u32x2*)&h1s[nxt][lr][sw1] = pk1;
        *(u32x2*)h1p        = pk0;
        *(u32x2*)(h1p + 16) = pk1;
        h1p += B_ * H_;

        cur = nxt;
    }
}

// -------- kernel 3 (swapped): Y[b][t][d] = bout[d] + sum_k H1[t][b][k]*Wout[d][k]
__global__ __launch_bounds__(256) void k_out(const unsigned short* __restrict__ H1,
                                             const float* __restrict__ Wout,
                                             const float* __restrict__ bout,
                                             float* __restrict__ out) {
    const int t  = blockIdx.x;
    const int bc = blockIdx.y;
    const int w  = threadIdx.x >> 6;
    const int l  = threadIdx.x & 63;
    const int lr = l & 15, lg = l >> 4;

    bf16x8 af[8];
    const unsigned short* hrow = H1 + ((size_t)t * B_ + bc * 16 + lr) * H_ + lg * 8;
#pragma unroll
    for (int kk = 0; kk < 8; kk++)
        af[kk] = __builtin_bit_cast(bf16x8, *(const u16x8*)(hrow + kk * 32));

#pragma unroll
    for (int i = 0; i < 2; i++) {
        const int n0 = (w + 4 * i) * 16;
        const float* wrow = Wout + (size_t)(n0 + lr) * H_ + lg * 8;
        float4 bv = *(const float4*)&bout[n0 + lg * 4];
        f32x4 acc = { bv.x, bv.y, bv.z, bv.w };
#pragma unroll
        for (int kk = 0; kk < 8; kk++) {
            bf16x8 bfr = ld8f_bf(wrow + kk * 32);
            acc = __builtin_amdgcn_mfma_f32_16x16x32_bf16(bfr, af[kk], acc, 0, 0, 0);
        }
        *(f32x4*)&out[((size_t)(bc * 16 + lr) * T_ + t) * DOUT_ + n0 + lg * 4] = acc;
    }
}

extern "C" void kernel_launch(void* const* d_in, const int* in_sizes, int n_in,
                              void* d_out, int out_size, void* d_ws, size_t ws_size,
                              hipStream_t stream) {
    const float* x    = (const float*)d_in[0];
    const float* h0   = (const float*)d_in[1];
    const float* Wx0  = (const float*)d_in[2];
    const float* Wh0  = (const float*)d_in[3];
    const float* b0   = (const float*)d_in[4];
    const float* Wx1  = (const float*)d_in[5];
    const float* Wh1  = (const float*)d_in[6];
    const float* b1   = (const float*)d_in[7];
    const float* Wout = (const float*)d_in[8];
    const float* bout = (const float*)d_in[9];
    float* out = (float*)d_out;

    unsigned short* Pre0 = (unsigned short*)d_ws;
    unsigned short* H1   = Pre0 + (size_t)T_ * B_ * H_;

    k_pre<<<dim3(T_, B_ / 16), 256, 0, stream>>>(x, Wx0, b0, Pre0);
    k_scan<<<dim3(4), 512, 0, stream>>>(h0, Wh0, Wx1, Wh1, b1, Pre0, H1);
    k_out<<<dim3(T_, B_ / 16), 256, 0, stream>>>(H1, Wout, bout, out);
}